// Round 9
// baseline (419.460 us; speedup 1.0000x reference)
//
#include <hip/hip_runtime.h>
#include <cstdint>
#include <cstddef>

// Problem constants (B,S,D,H) = (2, 2048, 256, 8)
#define S_LEN 2048
#define DIM   256
#define NH    8
#define NB    2
#define HDIM  (NH * DIM)   // 2048

using bf16 = __bf16;
typedef __bf16 bf16x8 __attribute__((ext_vector_type(8)));
typedef __bf16 bf16x4 __attribute__((ext_vector_type(4)));
typedef float  f32x4  __attribute__((ext_vector_type(4)));

typedef const __attribute__((address_space(1))) unsigned int* as1_u32p;
typedef __attribute__((address_space(3))) unsigned int* as3_u32p;

// async 16B global -> LDS (no VGPR round-trip). LDS dest = wave-uniform base
// + lane*16 (m104/m108).
__device__ __forceinline__ void cp16(const bf16* g, bf16* l) {
    __builtin_amdgcn_global_load_lds((as1_u32p)g, (as3_u32p)l, 16, 0, 0);
}

// ---------------------------------------------------------------------------
// Prep: fp32 -> bf16 cast; LDS-tiled transpose-casts (coalesced both sides).
// ---------------------------------------------------------------------------

__global__ __launch_bounds__(256) void cast_x_kernel(const float* __restrict__ in,
                                                     bf16* __restrict__ out) {
    int i = (blockIdx.x * 256 + threadIdx.x) * 4;
    float4 v = *(const float4*)(in + i);
    bf16x4 o;
    o[0] = (bf16)v.x; o[1] = (bf16)v.y; o[2] = (bf16)v.z; o[3] = (bf16)v.w;
    *(bf16x4*)(out + i) = o;
}

// Transpose-cast all three 256x256xH weight sets in one launch.
__global__ __launch_bounds__(256) void transpose_w3_kernel(const float* __restrict__ wQ,
                                                           const float* __restrict__ wK,
                                                           const float* __restrict__ wV,
                                                           bf16* __restrict__ WQt,
                                                           bf16* __restrict__ WKt,
                                                           bf16* __restrict__ WVt) {
    __shared__ float tile[64][65];
    const int z   = blockIdx.z;
    const int mat = z >> 3;
    const int h   = z & 7;
    const float* in = (mat == 0 ? wQ : mat == 1 ? wK : wV) + (size_t)h * DIM * DIM;
    bf16* out       = (mat == 0 ? WQt : mat == 1 ? WKt : WVt) + (size_t)h * DIM * DIM;
    const int c0 = blockIdx.x * 64, r0 = blockIdx.y * 64;
    const int tr  = threadIdx.x >> 4;
    const int tc4 = (threadIdx.x & 15) * 4;
    #pragma unroll
    for (int p = 0; p < 4; ++p) {
        int row = p * 16 + tr;
        float4 v = *(const float4*)(in + (size_t)(r0 + row) * DIM + c0 + tc4);
        tile[row][tc4+0] = v.x; tile[row][tc4+1] = v.y;
        tile[row][tc4+2] = v.z; tile[row][tc4+3] = v.w;
    }
    __syncthreads();
    #pragma unroll
    for (int p = 0; p < 4; ++p) {
        int orow = p * 16 + tr;
        bf16x4 o;
        #pragma unroll
        for (int j = 0; j < 4; ++j) o[j] = (bf16)tile[tc4 + j][orow];
        *(bf16x4*)(out + (size_t)(c0 + orow) * DIM + r0 + tc4) = o;
    }
}

// wO: [R][C] fp32 -> [C][R] bf16, 64x64 tiles. grid (C/64, R/64).
__global__ __launch_bounds__(256) void transpose_cast_kernel(const float* __restrict__ in,
                                                             bf16* __restrict__ out,
                                                             int R, int C) {
    __shared__ float tile[64][65];
    const int c0 = blockIdx.x * 64, r0 = blockIdx.y * 64;
    const int tr  = threadIdx.x >> 4;
    const int tc4 = (threadIdx.x & 15) * 4;
    #pragma unroll
    for (int p = 0; p < 4; ++p) {
        int row = p * 16 + tr;
        float4 v = *(const float4*)(in + (size_t)(r0 + row) * C + c0 + tc4);
        tile[row][tc4+0] = v.x; tile[row][tc4+1] = v.y;
        tile[row][tc4+2] = v.z; tile[row][tc4+3] = v.w;
    }
    __syncthreads();
    #pragma unroll
    for (int p = 0; p < 4; ++p) {
        int orow = p * 16 + tr;
        bf16x4 o;
        #pragma unroll
        for (int j = 0; j < 4; ++j) o[j] = (bf16)tile[tc4 + j][orow];
        *(bf16x4*)(out + (size_t)(c0 + orow) * R + r0 + tc4) = o;
    }
}

// ---------------------------------------------------------------------------
// 128x128-tile bf16 MFMA GEMM, ROUND-8-verified (async-DMA, XOR swizzle,
// single barrier per k-step). EPI: 0 bf16, 1 f32, 2 f32 atomicAdd.
// ---------------------------------------------------------------------------
template<int EPI>
__device__ __forceinline__ void gemm_tile(const bf16* __restrict__ A, const bf16* __restrict__ BT,
                                          void* __restrict__ C, bf16* As, bf16* Bs,
                                          int tm, int tn, int K, int lda, int ldb, int ldc)
{
    const int tid  = threadIdx.x;
    const int lane = tid & 63;
    const int wave = tid >> 6;
    const int wm   = (wave >> 1) << 6;
    const int wn   = (wave & 1) << 6;
    const int l16  = lane & 15;
    const int quad = lane >> 4;

    const int m0 = tm << 7, n0 = tn << 7;

    const int srow = (lane >> 2);
    const int gch  = (lane & 3) ^ (srow & 3);

    f32x4 acc[4][4] = {};

    const int ksteps = K >> 5;

    #pragma unroll
    for (int j = 0; j < 2; ++j) {
        const int g = wave*2 + j;
        cp16(A  + (size_t)(m0 + g*16 + srow)*lda + (gch << 3), As + g*512);
        cp16(BT + (size_t)(n0 + g*16 + srow)*ldb + (gch << 3), Bs + g*512);
    }

    for (int ks = 0; ks < ksteps; ++ks) {
        const int pb = ks & 1;
        asm volatile("s_waitcnt vmcnt(0)" ::: "memory");
        __syncthreads();
        if (ks + 1 < ksteps) {
            const int k1 = (ks + 1) << 5;
            #pragma unroll
            for (int j = 0; j < 2; ++j) {
                const int g = wave*2 + j;
                cp16(A  + (size_t)(m0 + g*16 + srow)*lda + k1 + (gch << 3),
                     As + (pb ^ 1)*4096 + g*512);
                cp16(BT + (size_t)(n0 + g*16 + srow)*ldb + k1 + (gch << 3),
                     Bs + (pb ^ 1)*4096 + g*512);
            }
        }
        const bf16* Ab = As + pb*4096;
        const bf16* Bb = Bs + pb*4096;
        bf16x8 af[4], bfv[4];
        #pragma unroll
        for (int i = 0; i < 4; ++i) {
            const int row = wm + i*16 + l16;
            af[i]  = *(const bf16x8*)(Ab + row*32 + ((quad ^ (l16 & 3)) << 3));
        }
        #pragma unroll
        for (int i = 0; i < 4; ++i) {
            const int row = wn + i*16 + l16;
            bfv[i] = *(const bf16x8*)(Bb + row*32 + ((quad ^ (l16 & 3)) << 3));
        }
        #pragma unroll
        for (int i = 0; i < 4; ++i)
            #pragma unroll
            for (int j = 0; j < 4; ++j)
                acc[i][j] = __builtin_amdgcn_mfma_f32_16x16x32_bf16(af[i], bfv[j], acc[i][j], 0, 0, 0);
    }

    #pragma unroll
    for (int i = 0; i < 4; ++i)
        #pragma unroll
        for (int j = 0; j < 4; ++j)
            #pragma unroll
            for (int r = 0; r < 4; ++r) {
                int mg = m0 + wm + i*16 + quad*4 + r;
                int ng = n0 + wn + j*16 + l16;
                float v = acc[i][j][r];
                if (EPI == 0)      ((bf16*)C)[(size_t)mg * ldc + ng] = (bf16)v;
                else if (EPI == 1) ((float*)C)[(size_t)mg * ldc + ng] = v;
                else               atomicAdd(&((float*)C)[(size_t)mg * ldc + ng], v);
            }
}

// QKV projections. grid = (32 tiles, 48 = {Q,K,V} x b x h). LDS 32 KB.
__global__ __launch_bounds__(256) void proj_kernel(const bf16* __restrict__ Xb,
    const bf16* __restrict__ WQt, const bf16* __restrict__ WKt, const bf16* __restrict__ WVt,
    bf16* __restrict__ Qg, bf16* __restrict__ Kg, bf16* __restrict__ VTg)
{
    __shared__ __align__(16) bf16 smem[4 * 4096];
    const int by  = blockIdx.y;
    const int mat = by >> 4;
    const int b   = (by >> 3) & 1;
    const int h   = by & 7;
    const int bx  = blockIdx.x;
    const bf16*  Xbb = Xb + (size_t)b * S_LEN * DIM;
    const size_t bh  = (size_t)(b * NH + h);
    if (mat == 0) {
        gemm_tile<0>(Xbb, WQt + (size_t)h*DIM*DIM, Qg + bh*S_LEN*DIM, smem, smem + 8192,
                     bx & 15, bx >> 4, DIM, DIM, DIM, DIM);
    } else if (mat == 1) {
        gemm_tile<0>(Xbb, WKt + (size_t)h*DIM*DIM, Kg + bh*S_LEN*DIM, smem, smem + 8192,
                     bx & 15, bx >> 4, DIM, DIM, DIM, DIM);
    } else {
        gemm_tile<0>(WVt + (size_t)h*DIM*DIM, Xbb, VTg + bh*DIM*S_LEN, smem, smem + 8192,
                     bx & 1, bx >> 1, DIM, DIM, DIM, S_LEN);
    }
}

// out[4096,256] += Ret[4096,2048(k-slice)] @ WOt^T, K-split x4. out pre-zeroed.
__global__ __launch_bounds__(256) void outproj_kernel(const bf16* __restrict__ Ret,
                                                      const bf16* __restrict__ WOt,
                                                      float* __restrict__ out)
{
    __shared__ __align__(16) bf16 smem[4 * 4096];
    int bx = blockIdx.x;
    int t  = bx & 63;
    int kq = bx >> 6;
    gemm_tile<2>(Ret + kq*512, WOt + kq*512, out, smem, smem + 8192,
                 t >> 1, t & 1, 512, HDIM, HDIM, DIM);
}

// ---------------------------------------------------------------------------
// Split-K flash causal attention (round 9): 2 waves x 32 q-rows each.
// Each wave owns TWO 16-row sets, so every K/V fragment read from LDS feeds
// 2 MFMAs -> per-block-step LDS reads drop 132 -> 68 (the round-8 analysis
// showed per-wave tile-read amplification is the serialized-resource cost).
// Same 64-row q-tiles, same 768-block grid, same R6-verified snake mapping,
// same R7/R8-verified swizzles, DMA staging, and no-max softmax.
// LDS 54272 B, block=128 threads -> 3 blocks/CU, VGPR ~235 (<256 @ 2 w/EU).
// ---------------------------------------------------------------------------
__global__ __launch_bounds__(128, 2) void attn_kernel(const bf16* __restrict__ Qg,
                                                      const bf16* __restrict__ Kg,
                                                      const bf16* __restrict__ VTg,
                                                      bf16* __restrict__ Ret,
                                                      bf16* __restrict__ Opart,
                                                      float* __restrict__ Lpart)
{
    __shared__ __align__(16) bf16 KsB[2][32 * 256];   // swizzled, unpadded
    __shared__ __align__(16) bf16 VTs[256 * 32];      // swizzled, single buffer
    __shared__ __align__(16) bf16 Ps [2 * 32 * 40];   // per-wave P tile (padded)

    const int tid  = threadIdx.x;
    const int lane = tid & 63;
    const int wave = tid >> 6;                       // 0 | 1
    const int l16  = lane & 15;
    const int quad = lane >> 4;

    // ---- work mapping (R6-verified snake over desc-length rank list) ----
    const int bx = blockIdx.x;                       // 0..767
    const int R  = (bx < 256) ? bx : (bx < 512 ? 767 - bx : bx);
    const int bh = R & 15;
    const int r  = R >> 4;                           // 0..47, desc length
    int qt, s; bool split;
    if (r < 40) {
        const int g = r / 5, j = r % 5;
        if (j == 0)      { qt = 15 - g;     split = false; s = 0; }
        else if (j <= 2) { qt = 31 - 2*g;   split = true;  s = j - 1; }
        else             { qt = 30 - 2*g;   split = true;  s = j - 3; }
    } else { qt = 47 - r; split = false; s = 0; }
    const int b = bh >> 3, h = bh & 7;

    int kstep0, kstep1;
    if (split) { kstep0 = s * (qt + 1); kstep1 = kstep0 + qt + 1; }
    else       { kstep0 = 0;           kstep1 = 2*qt + 2; }

    const bf16* Qbh  = Qg  + (size_t)(b*NH + h) * S_LEN * DIM;
    const bf16* Kbh  = Kg  + (size_t)(b*NH + h) * S_LEN * DIM;
    const bf16* VTbh = VTg + (size_t)(b*NH + h) * DIM * S_LEN;

    const int qbase = qt * 64 + wave * 32;           // this wave's 32 rows

    // Preload this wave's 32 Q rows as 2 row-sets x 8 A-frags
    bf16x8 qf[2][8];
    #pragma unroll
    for (int rs = 0; rs < 2; ++rs)
        #pragma unroll
        for (int kc = 0; kc < 8; ++kc)
            qf[rs][kc] = *(const bf16x8*)(Qbh + (size_t)(qbase + rs*16 + l16)*DIM + kc*32 + quad*8);

    f32x4 o[2][16] = {};              // 2 row-sets x (16 rows x 256 cols C-layout)
    float l_part[2][4] = {};

    // prologue: async-load first K tile into buffer 0 (16 DMA over 2 waves)
    {
        const int t00 = kstep0 << 5;
        #pragma unroll
        for (int j = 0; j < 8; ++j) {
            const int sN = (((wave << 3) + j) << 6) + lane;
            const int ts = sN >> 5, cs = sN & 31;
            cp16(Kbh + (size_t)(t00 + ts)*DIM + ((cs ^ ts) << 3),
                 &KsB[0][0] + (((wave << 3) + j) << 9));
        }
    }

    for (int step = kstep0; step < kstep1; ++step) {
        const int pb = (step - kstep0) & 1;
        asm volatile("s_waitcnt vmcnt(0)" ::: "memory");   // K buf pb DMA complete
        __syncthreads();

        const int t0 = step << 5;
        // stage V(t) (single buffer; drained by mid-barrier)
        #pragma unroll
        for (int j = 0; j < 8; ++j) {
            const int sN = (((wave << 3) + j) << 6) + lane;
            const int es = sN >> 2, cs = sN & 3;
            cp16(VTbh + (size_t)es*S_LEN + t0 + ((cs ^ ((es >> 1) & 3)) << 3),
                 &VTs[0] + (((wave << 3) + j) << 9));
        }
        // prefetch K(t+1)
        if (step + 1 < kstep1) {
            const int t1 = (step + 1) << 5;
            #pragma unroll
            for (int j = 0; j < 8; ++j) {
                const int sN = (((wave << 3) + j) << 6) + lane;
                const int ts = sN >> 5, cs = sN & 31;
                cp16(Kbh + (size_t)(t1 + ts)*DIM + ((cs ^ ts) << 3),
                     &KsB[pb ^ 1][0] + (((wave << 3) + j) << 9));
            }
        }

        const bf16* KsP = &KsB[pb][0];

        // S = Q K^T : 32 q-rows x 32 keys; each K-frag feeds 2 MFMAs
        f32x4 sacc[2][2] = {};        // [keytile][rowset]
        #pragma unroll
        for (int kc = 0; kc < 8; ++kc) {
            const int ch = (kc << 2) + quad;
            bf16x8 b0 = *(const bf16x8*)(KsP + (l16 << 8)        + ((ch ^ l16) << 3));
            bf16x8 b1 = *(const bf16x8*)(KsP + ((16 + l16) << 8) + ((ch ^ (16 + l16)) << 3));
            sacc[0][0] = __builtin_amdgcn_mfma_f32_16x16x32_bf16(qf[0][kc], b0, sacc[0][0], 0,0,0);
            sacc[0][1] = __builtin_amdgcn_mfma_f32_16x16x32_bf16(qf[1][kc], b0, sacc[0][1], 0,0,0);
            sacc[1][0] = __builtin_amdgcn_mfma_f32_16x16x32_bf16(qf[0][kc], b1, sacc[1][0], 0,0,0);
            sacc[1][1] = __builtin_amdgcn_mfma_f32_16x16x32_bf16(qf[1][kc], b1, sacc[1][1], 0,0,0);
        }

        // p = exp(s/16) masked; accumulate row-sums; write P straight to LDS
        #pragma unroll
        for (int rs = 0; rs < 2; ++rs)
            #pragma unroll
            for (int kt = 0; kt < 2; ++kt)
                #pragma unroll
                for (int r2 = 0; r2 < 4; ++r2) {
                    const int qgi = qbase + rs*16 + quad*4 + r2;
                    const bool ok = (t0 + kt*16 + l16) <= qgi;
                    float p = ok ? __expf(sacc[kt][rs][r2] * 0.0625f) : 0.0f;
                    l_part[rs][r2] += p;
                    Ps[wave*1280 + (rs*16 + quad*4 + r2)*40 + kt*16 + l16] = (bf16)p;
                }
        __syncthreads();              // Ps staged; drains V(t)+K(t+1) DMA

        bf16x8 pf0 = *(const bf16x8*)(Ps + wave*1280 + l16*40 + quad*8);
        bf16x8 pf1 = *(const bf16x8*)(Ps + wave*1280 + (16 + l16)*40 + quad*8);
        #pragma unroll
        for (int ct = 0; ct < 16; ++ct) {
            const int e = (ct << 4) + l16;
            bf16x8 vf = *(const bf16x8*)(&VTs[0] + (e << 5) + ((quad ^ ((e >> 1) & 3)) << 3));
            o[0][ct] = __builtin_amdgcn_mfma_f32_16x16x32_bf16(pf0, vf, o[0][ct], 0,0,0);
            o[1][ct] = __builtin_amdgcn_mfma_f32_16x16x32_bf16(pf1, vf, o[1][ct], 0,0,0);
        }
    }

    // row-sum reduction across the 16 key-lanes
    float lsum[2][4];
    #pragma unroll
    for (int rs = 0; rs < 2; ++rs)
        #pragma unroll
        for (int r2 = 0; r2 < 4; ++r2) {
            float l = l_part[rs][r2];
            l += __shfl_xor(l, 1);
            l += __shfl_xor(l, 2);
            l += __shfl_xor(l, 4);
            l += __shfl_xor(l, 8);
            lsum[rs][r2] = l;
        }

    if (!split) {
        #pragma unroll
        for (int rs = 0; rs < 2; ++rs)
            #pragma unroll
            for (int r2 = 0; r2 < 4; ++r2) {
                const int qgi = qbase + rs*16 + quad*4 + r2;
                const float inv = 1.0f / lsum[rs][r2];
                #pragma unroll
                for (int ct = 0; ct < 16; ++ct)
                    Ret[((size_t)b*S_LEN + qgi)*HDIM + h*DIM + ct*16 + l16] = (bf16)(o[rs][ct][r2] * inv);
            }
    } else {
        const size_t slot = ((size_t)(bh*16 + (qt - 16)))*2 + s;
        bf16*  Ob = Opart + slot * (64*256);
        float* Lb = Lpart + slot * 64;
        #pragma unroll
        for (int rs = 0; rs < 2; ++rs)
            #pragma unroll
            for (int r2 = 0; r2 < 4; ++r2) {
                const int trow = wave*32 + rs*16 + quad*4 + r2;
                #pragma unroll
                for (int ct = 0; ct < 16; ++ct)
                    Ob[(size_t)trow*256 + ct*16 + l16] = (bf16)o[rs][ct][r2];
                if (l16 == 0) Lb[trow] = lsum[rs][r2];
            }
    }
}

// Sum the two partials of each split q-tile, normalize, write Ret.
__global__ __launch_bounds__(256) void combine_kernel(const bf16* __restrict__ Opart,
                                                      const float* __restrict__ Lpart,
                                                      bf16* __restrict__ Ret)
{
    const int bx  = blockIdx.x;
    const int bh  = bx >> 4;
    const int qti = bx & 15;
    const int b = bh >> 3, h = bh & 7;
    const int row  = threadIdx.x >> 2;
    const int col0 = (threadIdx.x & 3) * 64;

    const size_t slot0 = ((size_t)(bh*16 + qti))*2;
    const bf16* O0 = Opart + slot0 * (64*256) + (size_t)row*256 + col0;
    const bf16* O1 = O0 + 64*256;
    const float inv = 1.0f / (Lpart[slot0*64 + row] + Lpart[(slot0+1)*64 + row]);

    const int q = (qti + 16)*64 + row;
    bf16* dst = Ret + ((size_t)b*S_LEN + q)*HDIM + h*DIM + col0;
    #pragma unroll
    for (int ch = 0; ch < 8; ++ch) {
        bf16x8 a = *(const bf16x8*)(O0 + ch*8);
        bf16x8 c = *(const bf16x8*)(O1 + ch*8);
        bf16x8 w;
        #pragma unroll
        for (int j = 0; j < 8; ++j) w[j] = (bf16)(((float)a[j] + (float)c[j]) * inv);
        *(bf16x8*)(dst + ch*8) = w;
    }
}

// ---------------------------------------------------------------------------

extern "C" void kernel_launch(void* const* d_in, const int* in_sizes, int n_in,
                              void* d_out, int out_size, void* d_ws, size_t ws_size,
                              hipStream_t stream)
{
    (void)in_sizes; (void)n_in; (void)ws_size;
    const float* X  = (const float*)d_in[0];
    // d_in[1] timestamp, d_in[6] theta: dead code in reference output
    const float* wQ = (const float*)d_in[2];
    const float* wK = (const float*)d_in[3];
    const float* wV = (const float*)d_in[4];
    const float* wO = (const float*)d_in[5];

    char* ws = (char*)d_ws;
    const size_t MB = 1u << 20;
    bf16*  Xb    = (bf16*)(ws + 0*MB);    // [B,S,D]        2 MB
    bf16*  WQt   = (bf16*)(ws + 2*MB);    // [H,E,D]        1 MB
    bf16*  WKt   = (bf16*)(ws + 3*MB);
    bf16*  WVt   = (bf16*)(ws + 4*MB);
    bf16*  WOt   = (bf16*)(ws + 5*MB);    // [D,H*D]        1 MB
    bf16*  Qg    = (bf16*)(ws + 6*MB);    // [B,H,S,D]     16 MB
    bf16*  Kg    = (bf16*)(ws + 22*MB);   // [B,H,S,D]     16 MB
    bf16*  VTg   = (bf16*)(ws + 38*MB);   // [B,H,D,S]     16 MB
    bf16*  Ret   = (bf16*)(ws + 54*MB);   // [B,S,H*D]     16 MB
    bf16*  Opart = (bf16*)(ws + 70*MB);   // [bh16][qti16][s2][64][256] bf16 = 16 MB
    float* Lpart = (float*)(ws + 86*MB);  // [bh16][qti16][s2][64] fp32 = 128 KB

    hipMemsetAsync(d_out, 0, (size_t)out_size * sizeof(float), stream);

    cast_x_kernel        <<<1024, 256, 0, stream>>>(X, Xb);
    transpose_w3_kernel  <<<dim3(4, 4, 24), 256, 0, stream>>>(wQ, wK, wV, WQt, WKt, WVt);
    transpose_cast_kernel<<<dim3(4, 32),    256, 0, stream>>>(wO, WOt, HDIM, DIM);
    proj_kernel    <<<dim3(32, 48), 256, 0, stream>>>(Xb, WQt, WKt, WVt, Qg, Kg, VTg);
    attn_kernel    <<<768,          128, 0, stream>>>(Qg, Kg, VTg, Ret, Opart, Lpart);
    combine_kernel <<<256,          256, 0, stream>>>(Opart, Lpart, Ret);
    outproj_kernel <<<256,          256, 0, stream>>>(Ret, WOt, (float*)d_out);
}

// Round 10
// 192.303 us; speedup vs baseline: 2.1812x; 2.1812x over previous
//
#include <hip/hip_runtime.h>
#include <cstdint>
#include <cstddef>

// Problem constants (B,S,D,H) = (2, 2048, 256, 8)
#define S_LEN 2048
#define DIM   256
#define NH    8
#define NB    2
#define HDIM  (NH * DIM)   // 2048

using bf16 = __bf16;
typedef __bf16 bf16x8 __attribute__((ext_vector_type(8)));
typedef __bf16 bf16x4 __attribute__((ext_vector_type(4)));
typedef float  f32x4  __attribute__((ext_vector_type(4)));

typedef const __attribute__((address_space(1))) unsigned int* as1_u32p;
typedef __attribute__((address_space(3))) unsigned int* as3_u32p;

// async 16B global -> LDS (no VGPR round-trip). LDS dest = wave-uniform base
// + lane*16 (m104/m108).
__device__ __forceinline__ void cp16(const bf16* g, bf16* l) {
    __builtin_amdgcn_global_load_lds((as1_u32p)g, (as3_u32p)l, 16, 0, 0);
}

// ---------------------------------------------------------------------------
// Prep: fp32 -> bf16 cast; LDS-tiled transpose-casts (coalesced both sides).
// ---------------------------------------------------------------------------

__global__ __launch_bounds__(256) void cast_x_kernel(const float* __restrict__ in,
                                                     bf16* __restrict__ out) {
    int i = (blockIdx.x * 256 + threadIdx.x) * 4;
    float4 v = *(const float4*)(in + i);
    bf16x4 o;
    o[0] = (bf16)v.x; o[1] = (bf16)v.y; o[2] = (bf16)v.z; o[3] = (bf16)v.w;
    *(bf16x4*)(out + i) = o;
}

// Transpose-cast all three 256x256xH weight sets in one launch.
__global__ __launch_bounds__(256) void transpose_w3_kernel(const float* __restrict__ wQ,
                                                           const float* __restrict__ wK,
                                                           const float* __restrict__ wV,
                                                           bf16* __restrict__ WQt,
                                                           bf16* __restrict__ WKt,
                                                           bf16* __restrict__ WVt) {
    __shared__ float tile[64][65];
    const int z   = blockIdx.z;
    const int mat = z >> 3;
    const int h   = z & 7;
    const float* in = (mat == 0 ? wQ : mat == 1 ? wK : wV) + (size_t)h * DIM * DIM;
    bf16* out       = (mat == 0 ? WQt : mat == 1 ? WKt : WVt) + (size_t)h * DIM * DIM;
    const int c0 = blockIdx.x * 64, r0 = blockIdx.y * 64;
    const int tr  = threadIdx.x >> 4;
    const int tc4 = (threadIdx.x & 15) * 4;
    #pragma unroll
    for (int p = 0; p < 4; ++p) {
        int row = p * 16 + tr;
        float4 v = *(const float4*)(in + (size_t)(r0 + row) * DIM + c0 + tc4);
        tile[row][tc4+0] = v.x; tile[row][tc4+1] = v.y;
        tile[row][tc4+2] = v.z; tile[row][tc4+3] = v.w;
    }
    __syncthreads();
    #pragma unroll
    for (int p = 0; p < 4; ++p) {
        int orow = p * 16 + tr;
        bf16x4 o;
        #pragma unroll
        for (int j = 0; j < 4; ++j) o[j] = (bf16)tile[tc4 + j][orow];
        *(bf16x4*)(out + (size_t)(c0 + orow) * DIM + r0 + tc4) = o;
    }
}

// wO: [R][C] fp32 -> [C][R] bf16, 64x64 tiles. grid (C/64, R/64).
__global__ __launch_bounds__(256) void transpose_cast_kernel(const float* __restrict__ in,
                                                             bf16* __restrict__ out,
                                                             int R, int C) {
    __shared__ float tile[64][65];
    const int c0 = blockIdx.x * 64, r0 = blockIdx.y * 64;
    const int tr  = threadIdx.x >> 4;
    const int tc4 = (threadIdx.x & 15) * 4;
    #pragma unroll
    for (int p = 0; p < 4; ++p) {
        int row = p * 16 + tr;
        float4 v = *(const float4*)(in + (size_t)(r0 + row) * C + c0 + tc4);
        tile[row][tc4+0] = v.x; tile[row][tc4+1] = v.y;
        tile[row][tc4+2] = v.z; tile[row][tc4+3] = v.w;
    }
    __syncthreads();
    #pragma unroll
    for (int p = 0; p < 4; ++p) {
        int orow = p * 16 + tr;
        bf16x4 o;
        #pragma unroll
        for (int j = 0; j < 4; ++j) o[j] = (bf16)tile[tc4 + j][orow];
        *(bf16x4*)(out + (size_t)(c0 + orow) * R + r0 + tc4) = o;
    }
}

// ---------------------------------------------------------------------------
// 128x128-tile bf16 MFMA GEMM, ROUND-8-verified (async-DMA, XOR swizzle,
// single barrier per k-step). EPI: 0 bf16, 1 f32, 2 f32 atomicAdd.
// ---------------------------------------------------------------------------
template<int EPI>
__device__ __forceinline__ void gemm_tile(const bf16* __restrict__ A, const bf16* __restrict__ BT,
                                          void* __restrict__ C, bf16* As, bf16* Bs,
                                          int tm, int tn, int K, int lda, int ldb, int ldc)
{
    const int tid  = threadIdx.x;
    const int lane = tid & 63;
    const int wave = tid >> 6;
    const int wm   = (wave >> 1) << 6;
    const int wn   = (wave & 1) << 6;
    const int l16  = lane & 15;
    const int quad = lane >> 4;

    const int m0 = tm << 7, n0 = tn << 7;

    const int srow = (lane >> 2);
    const int gch  = (lane & 3) ^ (srow & 3);

    f32x4 acc[4][4] = {};

    const int ksteps = K >> 5;

    #pragma unroll
    for (int j = 0; j < 2; ++j) {
        const int g = wave*2 + j;
        cp16(A  + (size_t)(m0 + g*16 + srow)*lda + (gch << 3), As + g*512);
        cp16(BT + (size_t)(n0 + g*16 + srow)*ldb + (gch << 3), Bs + g*512);
    }

    for (int ks = 0; ks < ksteps; ++ks) {
        const int pb = ks & 1;
        asm volatile("s_waitcnt vmcnt(0)" ::: "memory");
        __syncthreads();
        if (ks + 1 < ksteps) {
            const int k1 = (ks + 1) << 5;
            #pragma unroll
            for (int j = 0; j < 2; ++j) {
                const int g = wave*2 + j;
                cp16(A  + (size_t)(m0 + g*16 + srow)*lda + k1 + (gch << 3),
                     As + (pb ^ 1)*4096 + g*512);
                cp16(BT + (size_t)(n0 + g*16 + srow)*ldb + k1 + (gch << 3),
                     Bs + (pb ^ 1)*4096 + g*512);
            }
        }
        const bf16* Ab = As + pb*4096;
        const bf16* Bb = Bs + pb*4096;
        bf16x8 af[4], bfv[4];
        #pragma unroll
        for (int i = 0; i < 4; ++i) {
            const int row = wm + i*16 + l16;
            af[i]  = *(const bf16x8*)(Ab + row*32 + ((quad ^ (l16 & 3)) << 3));
        }
        #pragma unroll
        for (int i = 0; i < 4; ++i) {
            const int row = wn + i*16 + l16;
            bfv[i] = *(const bf16x8*)(Bb + row*32 + ((quad ^ (l16 & 3)) << 3));
        }
        #pragma unroll
        for (int i = 0; i < 4; ++i)
            #pragma unroll
            for (int j = 0; j < 4; ++j)
                acc[i][j] = __builtin_amdgcn_mfma_f32_16x16x32_bf16(af[i], bfv[j], acc[i][j], 0, 0, 0);
    }

    #pragma unroll
    for (int i = 0; i < 4; ++i)
        #pragma unroll
        for (int j = 0; j < 4; ++j)
            #pragma unroll
            for (int r = 0; r < 4; ++r) {
                int mg = m0 + wm + i*16 + quad*4 + r;
                int ng = n0 + wn + j*16 + l16;
                float v = acc[i][j][r];
                if (EPI == 0)      ((bf16*)C)[(size_t)mg * ldc + ng] = (bf16)v;
                else if (EPI == 1) ((float*)C)[(size_t)mg * ldc + ng] = v;
                else               atomicAdd(&((float*)C)[(size_t)mg * ldc + ng], v);
            }
}

// QKV projections. grid = (32 tiles, 48 = {Q,K,V} x b x h). LDS 32 KB.
__global__ __launch_bounds__(256) void proj_kernel(const bf16* __restrict__ Xb,
    const bf16* __restrict__ WQt, const bf16* __restrict__ WKt, const bf16* __restrict__ WVt,
    bf16* __restrict__ Qg, bf16* __restrict__ Kg, bf16* __restrict__ VTg)
{
    __shared__ __align__(16) bf16 smem[4 * 4096];
    const int by  = blockIdx.y;
    const int mat = by >> 4;
    const int b   = (by >> 3) & 1;
    const int h   = by & 7;
    const int bx  = blockIdx.x;
    const bf16*  Xbb = Xb + (size_t)b * S_LEN * DIM;
    const size_t bh  = (size_t)(b * NH + h);
    if (mat == 0) {
        gemm_tile<0>(Xbb, WQt + (size_t)h*DIM*DIM, Qg + bh*S_LEN*DIM, smem, smem + 8192,
                     bx & 15, bx >> 4, DIM, DIM, DIM, DIM);
    } else if (mat == 1) {
        gemm_tile<0>(Xbb, WKt + (size_t)h*DIM*DIM, Kg + bh*S_LEN*DIM, smem, smem + 8192,
                     bx & 15, bx >> 4, DIM, DIM, DIM, DIM);
    } else {
        gemm_tile<0>(WVt + (size_t)h*DIM*DIM, Xbb, VTg + bh*DIM*S_LEN, smem, smem + 8192,
                     bx & 1, bx >> 1, DIM, DIM, DIM, S_LEN);
    }
}

// out[4096,256] += Ret[4096,2048(k-slice)] @ WOt^T, K-split x4. out pre-zeroed.
__global__ __launch_bounds__(256) void outproj_kernel(const bf16* __restrict__ Ret,
                                                      const bf16* __restrict__ WOt,
                                                      float* __restrict__ out)
{
    __shared__ __align__(16) bf16 smem[4 * 4096];
    int bx = blockIdx.x;
    int t  = bx & 63;
    int kq = bx >> 6;
    gemm_tile<2>(Ret + kq*512, WOt + kq*512, out, smem, smem + 8192,
                 t >> 1, t & 1, 512, HDIM, HDIM, DIM);
}

// ---------------------------------------------------------------------------
// Split-K flash causal attention (round 10): R8-verified base (4 waves x 16
// q-rows QK, async DMA, swizzles, no-max softmax) + COLUMN-SPLIT PV:
// each wave computes ALL 64 q-rows x its own 64-col V strip. Valid because
// no-max softmax makes o a plain sum (no per-step rescale coupling rows).
// Per wave per step LDS reads: QK 16 + PV (4 P + 4 V) = 24, vs R8's 33.
// o accumulator stays 4x4 f32x4 = 64 VGPRs (same as R8; no spill).
// l broadcast at epilogue via LDS aliased into Ps (LDS stays 54272 B -> 3/CU).
// ---------------------------------------------------------------------------
__global__ __launch_bounds__(256) void attn_kernel(const bf16* __restrict__ Qg,
                                                   const bf16* __restrict__ Kg,
                                                   const bf16* __restrict__ VTg,
                                                   bf16* __restrict__ Ret,
                                                   bf16* __restrict__ Opart,
                                                   float* __restrict__ Lpart)
{
    __shared__ __align__(16) bf16 KsB[2][32 * 256];   // swizzled, unpadded
    __shared__ __align__(16) bf16 VTs[256 * 32];      // swizzled, single buffer
    __shared__ __align__(16) bf16 Ps [4 * 16 * 40];   // per-wave P tiles (padded)

    const int tid  = threadIdx.x;
    const int lane = tid & 63;
    const int wave = tid >> 6;
    const int l16  = lane & 15;
    const int quad = lane >> 4;

    // ---- work mapping (R6-verified snake over desc-length rank list) ----
    const int bx = blockIdx.x;                       // 0..767
    const int R  = (bx < 256) ? bx : (bx < 512 ? 767 - bx : bx);
    const int bh = R & 15;
    const int r  = R >> 4;                           // 0..47, desc length
    int qt, s; bool split;
    if (r < 40) {
        const int g = r / 5, j = r % 5;
        if (j == 0)      { qt = 15 - g;     split = false; s = 0; }
        else if (j <= 2) { qt = 31 - 2*g;   split = true;  s = j - 1; }
        else             { qt = 30 - 2*g;   split = true;  s = j - 3; }
    } else { qt = 47 - r; split = false; s = 0; }
    const int b = bh >> 3, h = bh & 7;

    int kstep0, kstep1;
    if (split) { kstep0 = s * (qt + 1); kstep1 = kstep0 + qt + 1; }
    else       { kstep0 = 0;           kstep1 = 2*qt + 2; }

    const bf16* Qbh  = Qg  + (size_t)(b*NH + h) * S_LEN * DIM;
    const bf16* Kbh  = Kg  + (size_t)(b*NH + h) * S_LEN * DIM;
    const bf16* VTbh = VTg + (size_t)(b*NH + h) * DIM * S_LEN;

    const int qbase = qt * 64 + wave * 16;           // QK: this wave's 16 rows
    const int colw  = wave << 6;                     // PV: this wave's 64-col strip

    // Preload this wave's 16 Q rows as 8 A-frags (full D=256)
    bf16x8 qf[8];
    #pragma unroll
    for (int kc = 0; kc < 8; ++kc)
        qf[kc] = *(const bf16x8*)(Qbh + (size_t)(qbase + l16)*DIM + kc*32 + quad*8);

    f32x4 o[4][4] = {};               // [rowtile][coltile]: 64 rows x 64 cols
    float l_part[4] = {0.f, 0.f, 0.f, 0.f};

    // prologue: async-load first K tile into buffer 0
    {
        const int t00 = kstep0 << 5;
        #pragma unroll
        for (int j = 0; j < 4; ++j) {
            const int sN = (((wave << 2) + j) << 6) + lane;
            const int ts = sN >> 5, cs = sN & 31;
            cp16(Kbh + (size_t)(t00 + ts)*DIM + ((cs ^ ts) << 3),
                 &KsB[0][0] + (((wave << 2) + j) << 9));
        }
    }

    for (int step = kstep0; step < kstep1; ++step) {
        const int pb = (step - kstep0) & 1;
        asm volatile("s_waitcnt vmcnt(0)" ::: "memory");   // K buf pb DMA complete
        __syncthreads();

        const int t0 = step << 5;
        // stage V(t) (single buffer; drained by mid-barrier)
        #pragma unroll
        for (int j = 0; j < 4; ++j) {
            const int sN = (((wave << 2) + j) << 6) + lane;
            const int es = sN >> 2, cs = sN & 3;
            cp16(VTbh + (size_t)es*S_LEN + t0 + ((cs ^ ((es >> 1) & 3)) << 3),
                 &VTs[0] + (((wave << 2) + j) << 9));
        }
        // prefetch K(t+1)
        if (step + 1 < kstep1) {
            const int t1 = (step + 1) << 5;
            #pragma unroll
            for (int j = 0; j < 4; ++j) {
                const int sN = (((wave << 2) + j) << 6) + lane;
                const int ts = sN >> 5, cs = sN & 31;
                cp16(Kbh + (size_t)(t1 + ts)*DIM + ((cs ^ ts) << 3),
                     &KsB[pb ^ 1][0] + (((wave << 2) + j) << 9));
            }
        }

        const bf16* KsP = &KsB[pb][0];

        // S = Q * K^T : 16 q-rows x 32 keys (XOR-swizzled K reads)
        f32x4 sacc[2] = {};
        #pragma unroll
        for (int kc = 0; kc < 8; ++kc) {
            const int ch = (kc << 2) + quad;
            bf16x8 b0 = *(const bf16x8*)(KsP + (l16 << 8)        + ((ch ^ l16) << 3));
            bf16x8 b1 = *(const bf16x8*)(KsP + ((16 + l16) << 8) + ((ch ^ (16 + l16)) << 3));
            sacc[0] = __builtin_amdgcn_mfma_f32_16x16x32_bf16(qf[kc], b0, sacc[0], 0,0,0);
            sacc[1] = __builtin_amdgcn_mfma_f32_16x16x32_bf16(qf[kc], b1, sacc[1], 0,0,0);
        }

        // p = exp(s/16) with causal mask; accumulate row-sum per-lane only
        float pv[2][4];
        #pragma unroll
        for (int r2 = 0; r2 < 4; ++r2) {
            const int qgi = qbase + quad*4 + r2;
            const bool ok0 = (t0 + l16)      <= qgi;
            const bool ok1 = (t0 + 16 + l16) <= qgi;
            float p0 = ok0 ? __expf(sacc[0][r2] * 0.0625f) : 0.0f;
            float p1 = ok1 ? __expf(sacc[1][r2] * 0.0625f) : 0.0f;
            l_part[r2] += p0 + p1;
            pv[0][r2] = p0; pv[1][r2] = p1;
        }

        // P: C-layout regs -> this wave's LDS region (rows 16*wave..16*wave+15)
        #pragma unroll
        for (int nt = 0; nt < 2; ++nt)
            #pragma unroll
            for (int r2 = 0; r2 < 4; ++r2)
                Ps[wave*640 + (quad*4 + r2)*40 + nt*16 + l16] = (bf16)pv[nt][r2];
        __syncthreads();              // all waves' P staged; drains V(t)+K(t+1) DMA

        // PV column-split: ALL 4 row-tiles x this wave's 4 col-tiles.
        // 4 P reads + 4 V reads feed 16 MFMAs.
        bf16x8 pf[4], vf[4];
        #pragma unroll
        for (int rt = 0; rt < 4; ++rt)
            pf[rt] = *(const bf16x8*)(Ps + rt*640 + l16*40 + quad*8);
        #pragma unroll
        for (int c2 = 0; c2 < 4; ++c2) {
            const int e = colw + (c2 << 4) + l16;
            vf[c2] = *(const bf16x8*)(&VTs[0] + (e << 5) + ((quad ^ ((e >> 1) & 3)) << 3));
        }
        #pragma unroll
        for (int rt = 0; rt < 4; ++rt)
            #pragma unroll
            for (int c2 = 0; c2 < 4; ++c2)
                o[rt][c2] = __builtin_amdgcn_mfma_f32_16x16x32_bf16(pf[rt], vf[c2], o[rt][c2], 0,0,0);
    }

    // row-sum reduction across the 16 key-lanes (this wave's 16 rows)
    float lsum[4];
    #pragma unroll
    for (int r2 = 0; r2 < 4; ++r2) {
        float l = l_part[r2];
        l += __shfl_xor(l, 1);
        l += __shfl_xor(l, 2);
        l += __shfl_xor(l, 4);
        l += __shfl_xor(l, 8);
        lsum[r2] = l;
    }

    // broadcast all 64 row-sums via LDS (alias into Ps; final Ps reads are done)
    __syncthreads();
    float* Lsh = (float*)Ps;
    if (l16 == 0) {
        #pragma unroll
        for (int r2 = 0; r2 < 4; ++r2) Lsh[wave*16 + quad*4 + r2] = lsum[r2];
    }
    __syncthreads();

    if (!split) {
        #pragma unroll
        for (int rt = 0; rt < 4; ++rt)
            #pragma unroll
            for (int r2 = 0; r2 < 4; ++r2) {
                const int row = rt*16 + quad*4 + r2;
                const float inv = 1.0f / Lsh[row];
                #pragma unroll
                for (int c2 = 0; c2 < 4; ++c2)
                    Ret[((size_t)b*S_LEN + qt*64 + row)*HDIM + h*DIM + colw + c2*16 + l16]
                        = (bf16)(o[rt][c2][r2] * inv);
            }
    } else {
        const size_t slot = ((size_t)(bh*16 + (qt - 16)))*2 + s;
        bf16*  Ob = Opart + slot * (64*256);
        float* Lb = Lpart + slot * 64;
        if (l16 == 0) {
            #pragma unroll
            for (int r2 = 0; r2 < 4; ++r2) Lb[wave*16 + quad*4 + r2] = lsum[r2];
        }
        #pragma unroll
        for (int rt = 0; rt < 4; ++rt)
            #pragma unroll
            for (int r2 = 0; r2 < 4; ++r2) {
                const int row = rt*16 + quad*4 + r2;
                #pragma unroll
                for (int c2 = 0; c2 < 4; ++c2)
                    Ob[(size_t)row*256 + colw + c2*16 + l16] = (bf16)o[rt][c2][r2];
            }
    }
}

// Sum the two partials of each split q-tile, normalize, write Ret.
__global__ __launch_bounds__(256) void combine_kernel(const bf16* __restrict__ Opart,
                                                      const float* __restrict__ Lpart,
                                                      bf16* __restrict__ Ret)
{
    const int bx  = blockIdx.x;
    const int bh  = bx >> 4;
    const int qti = bx & 15;
    const int b = bh >> 3, h = bh & 7;
    const int row  = threadIdx.x >> 2;
    const int col0 = (threadIdx.x & 3) * 64;

    const size_t slot0 = ((size_t)(bh*16 + qti))*2;
    const bf16* O0 = Opart + slot0 * (64*256) + (size_t)row*256 + col0;
    const bf16* O1 = O0 + 64*256;
    const float inv = 1.0f / (Lpart[slot0*64 + row] + Lpart[(slot0+1)*64 + row]);

    const int q = (qti + 16)*64 + row;
    bf16* dst = Ret + ((size_t)b*S_LEN + q)*HDIM + h*DIM + col0;
    #pragma unroll
    for (int ch = 0; ch < 8; ++ch) {
        bf16x8 a = *(const bf16x8*)(O0 + ch*8);
        bf16x8 c = *(const bf16x8*)(O1 + ch*8);
        bf16x8 w;
        #pragma unroll
        for (int j = 0; j < 8; ++j) w[j] = (bf16)(((float)a[j] + (float)c[j]) * inv);
        *(bf16x8*)(dst + ch*8) = w;
    }
}

// ---------------------------------------------------------------------------

extern "C" void kernel_launch(void* const* d_in, const int* in_sizes, int n_in,
                              void* d_out, int out_size, void* d_ws, size_t ws_size,
                              hipStream_t stream)
{
    (void)in_sizes; (void)n_in; (void)ws_size;
    const float* X  = (const float*)d_in[0];
    // d_in[1] timestamp, d_in[6] theta: dead code in reference output
    const float* wQ = (const float*)d_in[2];
    const float* wK = (const float*)d_in[3];
    const float* wV = (const float*)d_in[4];
    const float* wO = (const float*)d_in[5];

    char* ws = (char*)d_ws;
    const size_t MB = 1u << 20;
    bf16*  Xb    = (bf16*)(ws + 0*MB);    // [B,S,D]        2 MB
    bf16*  WQt   = (bf16*)(ws + 2*MB);    // [H,E,D]        1 MB
    bf16*  WKt   = (bf16*)(ws + 3*MB);
    bf16*  WVt   = (bf16*)(ws + 4*MB);
    bf16*  WOt   = (bf16*)(ws + 5*MB);    // [D,H*D]        1 MB
    bf16*  Qg    = (bf16*)(ws + 6*MB);    // [B,H,S,D]     16 MB
    bf16*  Kg    = (bf16*)(ws + 22*MB);   // [B,H,S,D]     16 MB
    bf16*  VTg   = (bf16*)(ws + 38*MB);   // [B,H,D,S]     16 MB
    bf16*  Ret   = (bf16*)(ws + 54*MB);   // [B,S,H*D]     16 MB
    bf16*  Opart = (bf16*)(ws + 70*MB);   // [bh16][qti16][s2][64][256] bf16 = 16 MB
    float* Lpart = (float*)(ws + 86*MB);  // [bh16][qti16][s2][64] fp32 = 128 KB

    hipMemsetAsync(d_out, 0, (size_t)out_size * sizeof(float), stream);

    cast_x_kernel        <<<1024, 256, 0, stream>>>(X, Xb);
    transpose_w3_kernel  <<<dim3(4, 4, 24), 256, 0, stream>>>(wQ, wK, wV, WQt, WKt, WVt);
    transpose_cast_kernel<<<dim3(4, 32),    256, 0, stream>>>(wO, WOt, HDIM, DIM);
    proj_kernel    <<<dim3(32, 48), 256, 0, stream>>>(Xb, WQt, WKt, WVt, Qg, Kg, VTg);
    attn_kernel    <<<768,          256, 0, stream>>>(Qg, Kg, VTg, Ret, Opart, Lpart);
    combine_kernel <<<256,          256, 0, stream>>>(Opart, Lpart, Ret);
    outproj_kernel <<<256,          256, 0, stream>>>(Ret, WOt, (float*)d_out);
}